// Round 6
// baseline (374.588 us; speedup 1.0000x reference)
//
#include <hip/hip_runtime.h>
#include <hip/hip_bf16.h>

typedef __attribute__((ext_vector_type(8))) short bf16x8;
typedef __attribute__((ext_vector_type(4))) float f32x4;
typedef __attribute__((ext_vector_type(16))) float f32x16;
typedef __attribute__((ext_vector_type(4))) int i32x4;

#define DEVI __device__ __forceinline__

namespace {
constexpr int BATCH = 2;
constexpr int T = 4096;
constexpr int C = 768;
constexpr int H = 12;
constexpr int HD = 64;
constexpr int M = BATCH * T;     // 8192
constexpr int N3 = 3 * C;        // 2304
constexpr int BH = BATCH * H;    // 24
constexpr float QSCALE = 0.125f * 1.44269504088896f;  // 1/sqrt(64) * log2(e)
}  // namespace

DEVI ushort f2b(float f) {
  union { float f; unsigned u; } v; v.f = f;
  unsigned r = (v.u + 0x7FFFu + ((v.u >> 16) & 1u)) >> 16;
  return (ushort)r;
}

DEVI f32x16 zero16() {
  f32x16 z;
#pragma unroll
  for (int i = 0; i < 16; i++) z[i] = 0.f;
  return z;
}

// async 16B global->LDS. LDS dest is wave-uniform base; HW adds lane*16.
DEVI void gload16(const void* g, void* l) {
  __builtin_amdgcn_global_load_lds(
      (const __attribute__((address_space(1))) unsigned int*)g,
      (__attribute__((address_space(3))) unsigned int*)l, 16, 0, 0);
}

__global__ __launch_bounds__(256) void cvt_kernel(const float* __restrict__ src,
                                                  ushort* __restrict__ dst, int n) {
  int i = (blockIdx.x * 256 + threadIdx.x) * 4;
  int stride = gridDim.x * 256 * 4;
  for (; i < n; i += stride) {
    float4 v = *reinterpret_cast<const float4*>(src + i);
    ushort4 o;
    o.x = f2b(v.x); o.y = f2b(v.y); o.z = f2b(v.z); o.w = f2b(v.w);
    *reinterpret_cast<ushort4*>(dst + i) = o;
  }
}

// Transpose-convert: f32 W [K][N] -> bf16 W^T [N][K]. 64x64 tiles.
__global__ __launch_bounds__(256) void cvtT_kernel(const float* __restrict__ src,
                                                   ushort* __restrict__ dst,
                                                   int K, int N) {
  __shared__ ushort Lt[64 * 68];
  const int k0 = blockIdx.x * 64, n0 = blockIdx.y * 64;
  const int tid = threadIdx.x;
  const int rr = tid >> 4, c4 = (tid & 15) * 4;
#pragma unroll
  for (int it = 0; it < 4; it++) {
    const int r = it * 16 + rr;
    float4 v = *reinterpret_cast<const float4*>(src + (size_t)(k0 + r) * N + n0 + c4);
    Lt[(c4 + 0) * 68 + r] = f2b(v.x);
    Lt[(c4 + 1) * 68 + r] = f2b(v.y);
    Lt[(c4 + 2) * 68 + r] = f2b(v.z);
    Lt[(c4 + 3) * 68 + r] = f2b(v.w);
  }
  __syncthreads();
#pragma unroll
  for (int it = 0; it < 4; it++) {
    const int r = it * 16 + rr;
    *reinterpret_cast<ushort4*>(dst + (size_t)(n0 + r) * K + k0 + c4) =
        *reinterpret_cast<const ushort4*>(&Lt[r * 68 + c4]);
  }
}

// m97-style GEMM: A [Mrows x Kd] bf16 row-major, Bt = B^T [N x Kd] bf16 row-major.
// 32x32x16 MFMA, gload_lds staging with XOR-8 k-swizzle, BK=64, 256 thr = 4 waves.
// EPI=0: BM=128,BN=128, QKV epilogue (Q scaled [bh][t][d]; K plain [bh][t][d];
//        V transposed kv-tiled [bh][t/64][d][64]).
// EPI=1: BM=64, BN=128, f32 out + bias.
template <int EPI>
__global__ __launch_bounds__(256, 3) void gemm_kernel(
    const ushort* __restrict__ A, const ushort* __restrict__ Bt,
    const float* __restrict__ bias, int N, int Kd,
    ushort* __restrict__ qo, ushort* __restrict__ ko, ushort* __restrict__ vo,
    float* __restrict__ fo) {
  constexpr int BM = (EPI == 0) ? 128 : 64;
  constexpr int BN = 128;
  constexpr int WN = (EPI == 0) ? 2 : 4;   // waves along n
  constexpr int WTN = BN / WN;             // 64 or 32
  constexpr int NT = WTN / 32;             // 2 or 1
  constexpr int CH_A = BM / 8;             // 1KB chunks in A tile
  constexpr int CH_B = BN / 8;
  constexpr int CPW = (CH_A + CH_B) / 4;
  constexpr int SMEM = (EPI == 0) ? (4 * 64 * 68) : ((BM + BN) * 64);
  __shared__ ushort smem[SMEM];
  ushort* As = smem;
  ushort* Bs = smem + BM * 64;

  const int tid = threadIdx.x;
  const int lane = tid & 63;
  const int w = tid >> 6;
  const int l31 = lane & 31;
  const int hi = lane >> 5;
  const int wm = w / WN, wn = w % WN;
  const int m0 = blockIdx.y * BM, n0 = blockIdx.x * BN;
  const int r8 = lane >> 3, c8 = lane & 7;
  const int csw = (c8 ^ r8) * 8;

  f32x16 acc[2][NT];
#pragma unroll
  for (int mt = 0; mt < 2; mt++)
#pragma unroll
    for (int nt = 0; nt < NT; nt++) acc[mt][nt] = zero16();

  for (int k0 = 0; k0 < Kd; k0 += 64) {
    __syncthreads();
#pragma unroll
    for (int ci = 0; ci < CPW; ci++) {
      const int chk = w * CPW + ci;
      if (chk < CH_A) {
        gload16(A + (size_t)(m0 + chk * 8 + r8) * Kd + k0 + csw, (char*)As + chk * 1024);
      } else {
        const int ch2 = chk - CH_A;
        gload16(Bt + (size_t)(n0 + ch2 * 8 + r8) * Kd + k0 + csw, (char*)Bs + ch2 * 1024);
      }
    }
    __syncthreads();
#pragma unroll
    for (int ks = 0; ks < 4; ks++) {
      bf16x8 af[2], bf[NT];
#pragma unroll
      for (int mt = 0; mt < 2; mt++) {
        const int rl = wm * 64 + mt * 32 + l31;
        af[mt] = *reinterpret_cast<const bf16x8*>(
            &As[rl * 64 + ((ks * 16 + hi * 8) ^ ((rl & 7) * 8))]);
      }
#pragma unroll
      for (int nt = 0; nt < NT; nt++) {
        const int nl = wn * WTN + nt * 32 + l31;
        bf[nt] = *reinterpret_cast<const bf16x8*>(
            &Bs[nl * 64 + ((ks * 16 + hi * 8) ^ ((nl & 7) * 8))]);
      }
#pragma unroll
      for (int mt = 0; mt < 2; mt++)
#pragma unroll
        for (int nt = 0; nt < NT; nt++)
          acc[mt][nt] = __builtin_amdgcn_mfma_f32_32x32x16_bf16(af[mt], bf[nt], acc[mt][nt], 0, 0, 0);
    }
  }

  // C layout (verified): col = l31, row = (r&3) + 8*(r>>2) + 4*hi
  if constexpr (EPI == 0) {
    if (n0 >= 1536) {
      // V tile: bias, per-wave transpose via LDS, store V^T kv-tiled [bh][tile][d][kv]
      __syncthreads();
      ushort* Vw = smem + w * 4352;  // [64 d][68]
      const float bv0 = bias[n0 + wn * 64 + l31];
      const float bv1 = bias[n0 + wn * 64 + 32 + l31];
#pragma unroll
      for (int mt = 0; mt < 2; mt++)
#pragma unroll
        for (int nt = 0; nt < 2; nt++) {
          const float bv = nt ? bv1 : bv0;
#pragma unroll
          for (int r = 0; r < 16; r++) {
            const int trow = mt * 32 + (r & 3) + ((r >> 2) << 3) + (hi << 2);
            Vw[(nt * 32 + l31) * 68 + trow] = f2b(acc[mt][nt][r] + bv);
          }
        }
      const int hh = (n0 - 1536) / 64 + wn;
      const int bb = m0 >> 12;
      const int t0 = (m0 & (T - 1)) + wm * 64;
      const size_t vbase = ((size_t)((bb * H + hh) * 64 + (t0 >> 6)) * 64 + lane) * 64;
#pragma unroll
      for (int x8 = 0; x8 < 8; x8++) {
        bf16x8 vv = *reinterpret_cast<const bf16x8*>(&Vw[lane * 68 + x8 * 8]);
        *reinterpret_cast<bf16x8*>(vo + vbase + x8 * 8) = vv;
      }
    } else {
#pragma unroll
      for (int mt = 0; mt < 2; mt++)
#pragma unroll
        for (int nt = 0; nt < 2; nt++) {
          const int n = n0 + wn * 64 + nt * 32 + l31;
          const float bv = bias[n];
          const int part = (n >= 768) ? 1 : 0;
          const int ci = n - part * 768;
          const int hh = ci >> 6, dd = ci & 63;
#pragma unroll
          for (int r = 0; r < 16; r++) {
            const int m = m0 + wm * 64 + mt * 32 + (r & 3) + ((r >> 2) << 3) + (hi << 2);
            const int bb = m >> 12, t = m & (T - 1);
            const float val = acc[mt][nt][r] + bv;
            if (part == 0) {
              qo[((size_t)(bb * H + hh) * T + t) * HD + dd] = f2b(val * QSCALE);
            } else {
              ko[((size_t)(bb * H + hh) * T + t) * HD + dd] = f2b(val);
            }
          }
        }
    }
  } else {
#pragma unroll
    for (int mt = 0; mt < 2; mt++)
#pragma unroll
      for (int nt = 0; nt < NT; nt++) {
        const int n = n0 + wn * WTN + nt * 32 + l31;
        const float bv = bias[n];
#pragma unroll
        for (int r = 0; r < 16; r++) {
          const int m = m0 + wm * 64 + mt * 32 + (r & 3) + ((r >> 2) << 3) + (hi << 2);
          fo[(size_t)m * N + n] = acc[mt][nt][r] + bv;
        }
      }
  }
}

// Flash attention v6: barrier-free, one wave per block, operands direct from L2.
// 3072 blocks = 24 bh x 128 q-jobs (32 q each); heavy-first, XCD-grouped.
// Swapped QK^T (S^T per-lane softmax), O^T accumulation, 32x32x16 MFMA.
__global__ __launch_bounds__(64, 3) void attn_kernel(
    const ushort* __restrict__ Qg, const ushort* __restrict__ Kg,
    const ushort* __restrict__ Vtg, ushort* __restrict__ Yg) {
  __shared__ ushort Yt[32 * 68];

  const int lane = threadIdx.x;
  const int l31 = lane & 31;
  const int hi = lane >> 5;

  const int bid = blockIdx.x;
  const int xcd = bid & 7, idx = bid >> 3;   // 8 XCDs x 384
  const int bh = xcd * 3 + idx % 3;          // 3 heads per XCD (K+V 3MB -> L2 resident)
  const int j = 127 - idx / 3;               // heavy jobs dispatched first
  const int q0 = j * 32;
  const int qc = q0 + l31;                   // this lane's q row
  const int ntiles = (j + 2) >> 1;           // ceil((j+1)/2) KVBLK=64 tiles

  const ushort* Qp = Qg + (size_t)bh * (T * HD);
  // K frag (A of mfma(K,Q)): row kv0+sub*32+l31, cols ks*16+hi*8 (+8)
  const char* kaddr = (const char*)(Kg + (size_t)bh * (T * HD)) + l31 * 128 + hi * 16;
  // V frag (A of mfma(V^T,P^T)): Vt tiled [bh][tile][d][kv64]; row d=dt*32+l31, col slice*16+hi*8
  const char* vaddr = (const char*)(Vtg + (size_t)bh * (HD * T)) + l31 * 128 + hi * 16;

  // Q B-fragments: B[k=ks*16+hi*8+jj][n=q=l31]
  bf16x8 qf[4];
#pragma unroll
  for (int ks = 0; ks < 4; ks++)
    qf[ks] = *reinterpret_cast<const bf16x8*>(Qp + (size_t)qc * HD + ks * 16 + hi * 8);

  float mrun = -1e30f, lrun = 0.f;
  f32x16 o16[2];
  o16[0] = zero16();
  o16[1] = zero16();

  bf16x8 kf[2][4], vf[2][4];

  // prologue: K tile 0
#pragma unroll
  for (int sub = 0; sub < 2; sub++)
#pragma unroll
    for (int ks = 0; ks < 4; ks++)
      kf[sub][ks] = *reinterpret_cast<const bf16x8*>(kaddr + sub * 4096 + ks * 32);

  for (int tt = 0; tt < ntiles; tt++) {
    const bool last = (tt == ntiles - 1);
    const bool h1 = !last || (j & 1);  // sub1 present?

    // V loads for this tile (consumed ~400cyc later at PV)
#pragma unroll
    for (int dt = 0; dt < 2; dt++)
#pragma unroll
      for (int sl = 0; sl < 4; sl++)
        vf[dt][sl] = *reinterpret_cast<const bf16x8*>(vaddr + dt * 4096 + sl * 32);

    // S^T = K x Q^T
    f32x16 s0 = zero16(), s1 = zero16();
    __builtin_amdgcn_s_setprio(1);
#pragma unroll
    for (int ks = 0; ks < 4; ks++)
      s0 = __builtin_amdgcn_mfma_f32_32x32x16_bf16(kf[0][ks], qf[ks], s0, 0, 0, 0);
    if (h1) {
#pragma unroll
      for (int ks = 0; ks < 4; ks++)
        s1 = __builtin_amdgcn_mfma_f32_32x32x16_bf16(kf[1][ks], qf[ks], s1, 0, 0, 0);
    }
    __builtin_amdgcn_s_setprio(0);

    // issue K loads for next tile (hidden under softmax + PV)
    kaddr += 8192;
    if (!last) {
#pragma unroll
      for (int sub = 0; sub < 2; sub++)
#pragma unroll
        for (int ks = 0; ks < 4; ks++)
          kf[sub][ks] = *reinterpret_cast<const bf16x8*>(kaddr + sub * 4096 + ks * 32);
    }

    // causal mask (diagonal tile only): kv = kv0 + sub*32 + crow(r,hi)
    if (last) {
      const int kvb = tt * 64;
      if ((j & 1) == 0) {
#pragma unroll
        for (int r2 = 0; r2 < 16; r2++) {
          const int kv = kvb + (r2 & 3) + ((r2 >> 2) << 3) + (hi << 2);
          if (kv > qc) s0[r2] = -1e30f;
        }
      } else {
#pragma unroll
        for (int r2 = 0; r2 < 16; r2++) {
          const int kv = kvb + 32 + (r2 & 3) + ((r2 >> 2) << 3) + (hi << 2);
          if (kv > qc) s1[r2] = -1e30f;
        }
      }
    }

    // online softmax (per-lane q=l31; lane^32 holds the other row-half)
    float pa = s0[0], pb = s0[1], pc = s0[2], pd = s0[3];
#pragma unroll
    for (int r2 = 4; r2 < 16; r2 += 4) {
      pa = fmaxf(pa, s0[r2]); pb = fmaxf(pb, s0[r2 + 1]);
      pc = fmaxf(pc, s0[r2 + 2]); pd = fmaxf(pd, s0[r2 + 3]);
    }
    if (h1) {
#pragma unroll
      for (int r2 = 0; r2 < 16; r2 += 4) {
        pa = fmaxf(pa, s1[r2]); pb = fmaxf(pb, s1[r2 + 1]);
        pc = fmaxf(pc, s1[r2 + 2]); pd = fmaxf(pd, s1[r2 + 3]);
      }
    }
    float pm = fmaxf(fmaxf(pa, pb), fmaxf(pc, pd));
    pm = fmaxf(pm, __shfl_xor(pm, 32));
    if (__any(pm > mrun + 8.f)) {  // defer-max THR=8 (exp2 space)
      const float mnew = fmaxf(mrun, pm);
      const float corr = __builtin_amdgcn_exp2f(mrun - mnew);
      lrun *= corr;
#pragma unroll
      for (int dt = 0; dt < 2; dt++)
#pragma unroll
        for (int r2 = 0; r2 < 16; r2++) o16[dt][r2] *= corr;
      mrun = mnew;
    }
    float sa = 0.f, sb = 0.f, sc = 0.f, sd = 0.f;
#pragma unroll
    for (int r2 = 0; r2 < 16; r2 += 4) {
      s0[r2] = __builtin_amdgcn_exp2f(s0[r2] - mrun);           sa += s0[r2];
      s0[r2 + 1] = __builtin_amdgcn_exp2f(s0[r2 + 1] - mrun);   sb += s0[r2 + 1];
      s0[r2 + 2] = __builtin_amdgcn_exp2f(s0[r2 + 2] - mrun);   sc += s0[r2 + 2];
      s0[r2 + 3] = __builtin_amdgcn_exp2f(s0[r2 + 3] - mrun);   sd += s0[r2 + 3];
    }
    if (h1) {
#pragma unroll
      for (int r2 = 0; r2 < 16; r2 += 4) {
        s1[r2] = __builtin_amdgcn_exp2f(s1[r2] - mrun);         sa += s1[r2];
        s1[r2 + 1] = __builtin_amdgcn_exp2f(s1[r2 + 1] - mrun); sb += s1[r2 + 1];
        s1[r2 + 2] = __builtin_amdgcn_exp2f(s1[r2 + 2] - mrun); sc += s1[r2 + 2];
        s1[r2 + 3] = __builtin_amdgcn_exp2f(s1[r2 + 3] - mrun); sd += s1[r2 + 3];
      }
    }
    float sum = (sa + sb) + (sc + sd);
    sum += __shfl_xor(sum, 32);
    lrun += sum;

    // P^T B-frag in-register (cvt_pk + permlane32_swap), then O^T += V^T x P^T
#pragma unroll
    for (int sub = 0; sub < 2; sub++) {
      if (sub == 1 && !h1) continue;
#pragma unroll
      for (int ks2 = 0; ks2 < 2; ks2++) {
        const int r0 = ks2 * 8;
        int a0, a1, b0, b1;
        if (sub == 0) {
          asm("v_cvt_pk_bf16_f32 %0, %1, %2" : "=v"(a0) : "v"(s0[r0 + 0]), "v"(s0[r0 + 1]));
          asm("v_cvt_pk_bf16_f32 %0, %1, %2" : "=v"(a1) : "v"(s0[r0 + 2]), "v"(s0[r0 + 3]));
          asm("v_cvt_pk_bf16_f32 %0, %1, %2" : "=v"(b0) : "v"(s0[r0 + 4]), "v"(s0[r0 + 5]));
          asm("v_cvt_pk_bf16_f32 %0, %1, %2" : "=v"(b1) : "v"(s0[r0 + 6]), "v"(s0[r0 + 7]));
        } else {
          asm("v_cvt_pk_bf16_f32 %0, %1, %2" : "=v"(a0) : "v"(s1[r0 + 0]), "v"(s1[r0 + 1]));
          asm("v_cvt_pk_bf16_f32 %0, %1, %2" : "=v"(a1) : "v"(s1[r0 + 2]), "v"(s1[r0 + 3]));
          asm("v_cvt_pk_bf16_f32 %0, %1, %2" : "=v"(b0) : "v"(s1[r0 + 4]), "v"(s1[r0 + 5]));
          asm("v_cvt_pk_bf16_f32 %0, %1, %2" : "=v"(b1) : "v"(s1[r0 + 6]), "v"(s1[r0 + 7]));
        }
        asm("v_permlane32_swap_b32 %0, %1" : "+v"(a0), "+v"(b0));
        asm("v_permlane32_swap_b32 %0, %1" : "+v"(a1), "+v"(b1));
        const i32x4 pi = {a0, a1, b0, b1};
        const bf16x8 pf = __builtin_bit_cast(bf16x8, pi);
        __builtin_amdgcn_s_setprio(1);
        o16[0] = __builtin_amdgcn_mfma_f32_32x32x16_bf16(vf[0][sub * 2 + ks2], pf, o16[0], 0, 0, 0);
        o16[1] = __builtin_amdgcn_mfma_f32_32x32x16_bf16(vf[1][sub * 2 + ks2], pf, o16[1], 0, 0, 0);
        __builtin_amdgcn_s_setprio(0);
      }
    }
    vaddr += 8192;
  }  // tt

  // epilogue: O^T -> LDS transpose -> coalesced Y write (single wave, no barrier races)
  const int bb = bh / H, h = bh % H;
  const float linv = 1.0f / lrun;
#pragma unroll
  for (int dt = 0; dt < 2; dt++)
#pragma unroll
    for (int r2 = 0; r2 < 16; r2++) {
      const int d = dt * 32 + (r2 & 3) + ((r2 >> 2) << 3) + (hi << 2);
      Yt[l31 * 68 + d] = f2b(o16[dt][r2] * linv);
    }
  __syncthreads();
  {
    const int row = lane >> 1, half = lane & 1;
#pragma unroll
    for (int seg = 0; seg < 4; seg++) {
      bf16x8 vv = *reinterpret_cast<const bf16x8*>(&Yt[row * 68 + half * 32 + seg * 8]);
      *reinterpret_cast<bf16x8*>(
          Yg + ((size_t)(bb * T + q0 + row)) * C + h * 64 + half * 32 + seg * 8) = vv;
    }
  }
}

extern "C" void kernel_launch(void* const* d_in, const int* in_sizes, int n_in,
                              void* d_out, int out_size, void* d_ws, size_t ws_size,
                              hipStream_t stream) {
  const float* x = (const float*)d_in[0];
  const float* Wa = (const float*)d_in[1];
  const float* ba = (const float*)d_in[2];
  const float* Wp = (const float*)d_in[3];
  const float* bp = (const float*)d_in[4];
  float* out = (float*)d_out;

  char* ws = (char*)d_ws;
  size_t off = 0;
  auto carve = [&](size_t bytes) {
    void* p = ws + off;
    off += (bytes + 255) & ~(size_t)255;
    return p;
  };
  ushort* xb   = (ushort*)carve((size_t)M * C * 2);
  ushort* WaT  = (ushort*)carve((size_t)N3 * C * 2);
  ushort* WpT  = (ushort*)carve((size_t)C * C * 2);
  ushort* Qb   = (ushort*)carve((size_t)BH * T * HD * 2);
  ushort* Kb   = (ushort*)carve((size_t)BH * T * HD * 2);
  ushort* Vtb  = (ushort*)carve((size_t)BH * HD * T * 2);
  ushort* Yb   = (ushort*)carve((size_t)M * C * 2);

  cvt_kernel<<<2048, 256, 0, stream>>>(x, xb, M * C);
  cvtT_kernel<<<dim3(C / 64, N3 / 64), 256, 0, stream>>>(Wa, WaT, C, N3);
  cvtT_kernel<<<dim3(C / 64, C / 64), 256, 0, stream>>>(Wp, WpT, C, C);

  gemm_kernel<0><<<dim3(N3 / 128, M / 128), 256, 0, stream>>>(
      xb, WaT, ba, N3, C, Qb, Kb, Vtb, nullptr);

  attn_kernel<<<dim3(3072), 64, 0, stream>>>(Qb, Kb, Vtb, Yb);

  gemm_kernel<1><<<dim3(C / 128, M / 64), 256, 0, stream>>>(
      Yb, WpT, bp, C, C, nullptr, nullptr, nullptr, out);
}

// Round 7
// 197.072 us; speedup vs baseline: 1.9008x; 1.9008x over previous
//
#include <hip/hip_runtime.h>
#include <hip/hip_bf16.h>

typedef __attribute__((ext_vector_type(8))) short bf16x8;
typedef __attribute__((ext_vector_type(4))) float f32x4;
typedef __attribute__((ext_vector_type(16))) float f32x16;
typedef __attribute__((ext_vector_type(4))) int i32x4;

#define DEVI __device__ __forceinline__

namespace {
constexpr int BATCH = 2;
constexpr int T = 4096;
constexpr int C = 768;
constexpr int H = 12;
constexpr int HD = 64;
constexpr int M = BATCH * T;     // 8192
constexpr int N3 = 3 * C;        // 2304
constexpr int BH = BATCH * H;    // 24
constexpr float QSCALE = 0.125f * 1.44269504088896f;  // 1/sqrt(64) * log2(e)
}  // namespace

DEVI ushort f2b(float f) {
  union { float f; unsigned u; } v; v.f = f;
  unsigned r = (v.u + 0x7FFFu + ((v.u >> 16) & 1u)) >> 16;
  return (ushort)r;
}

DEVI f32x16 zero16() {
  f32x16 z;
#pragma unroll
  for (int i = 0; i < 16; i++) z[i] = 0.f;
  return z;
}

// async 16B global->LDS. LDS dest is wave-uniform base; HW adds lane*16.
DEVI void gload16(const void* g, void* l) {
  __builtin_amdgcn_global_load_lds(
      (const __attribute__((address_space(1))) unsigned int*)g,
      (__attribute__((address_space(3))) unsigned int*)l, 16, 0, 0);
}

__global__ __launch_bounds__(256) void cvt_kernel(const float* __restrict__ src,
                                                  ushort* __restrict__ dst, int n) {
  int i = (blockIdx.x * 256 + threadIdx.x) * 4;
  int stride = gridDim.x * 256 * 4;
  for (; i < n; i += stride) {
    float4 v = *reinterpret_cast<const float4*>(src + i);
    ushort4 o;
    o.x = f2b(v.x); o.y = f2b(v.y); o.z = f2b(v.z); o.w = f2b(v.w);
    *reinterpret_cast<ushort4*>(dst + i) = o;
  }
}

// Transpose-convert: f32 W [K][N] -> bf16 W^T [N][K]. 64x64 tiles.
__global__ __launch_bounds__(256) void cvtT_kernel(const float* __restrict__ src,
                                                   ushort* __restrict__ dst,
                                                   int K, int N) {
  __shared__ ushort Lt[64 * 68];
  const int k0 = blockIdx.x * 64, n0 = blockIdx.y * 64;
  const int tid = threadIdx.x;
  const int rr = tid >> 4, c4 = (tid & 15) * 4;
#pragma unroll
  for (int it = 0; it < 4; it++) {
    const int r = it * 16 + rr;
    float4 v = *reinterpret_cast<const float4*>(src + (size_t)(k0 + r) * N + n0 + c4);
    Lt[(c4 + 0) * 68 + r] = f2b(v.x);
    Lt[(c4 + 1) * 68 + r] = f2b(v.y);
    Lt[(c4 + 2) * 68 + r] = f2b(v.z);
    Lt[(c4 + 3) * 68 + r] = f2b(v.w);
  }
  __syncthreads();
#pragma unroll
  for (int it = 0; it < 4; it++) {
    const int r = it * 16 + rr;
    *reinterpret_cast<ushort4*>(dst + (size_t)(n0 + r) * K + k0 + c4) =
        *reinterpret_cast<const ushort4*>(&Lt[r * 68 + c4]);
  }
}

// m97-style GEMM: A [Mrows x Kd] bf16 row-major, Bt = B^T [N x Kd] bf16 row-major.
// 32x32x16 MFMA, gload_lds staging with XOR-8 k-swizzle, BK=64, 256 thr = 4 waves.
// EPI=0: BM=128,BN=128, QKV epilogue (Q scaled; K d-swizzled; V transposed+t-swizzled).
// EPI=1: BM=64, BN=128, f32 out + bias.
template <int EPI>
__global__ __launch_bounds__(256, 3) void gemm_kernel(
    const ushort* __restrict__ A, const ushort* __restrict__ Bt,
    const float* __restrict__ bias, int N, int Kd,
    ushort* __restrict__ qo, ushort* __restrict__ ko, ushort* __restrict__ vo,
    float* __restrict__ fo) {
  constexpr int BM = (EPI == 0) ? 128 : 64;
  constexpr int BN = 128;
  constexpr int WN = (EPI == 0) ? 2 : 4;   // waves along n
  constexpr int WTN = BN / WN;             // 64 or 32
  constexpr int NT = WTN / 32;             // 2 or 1
  constexpr int CH_A = BM / 8;             // 1KB chunks in A tile
  constexpr int CH_B = BN / 8;
  constexpr int CPW = (CH_A + CH_B) / 4;
  constexpr int SMEM = (EPI == 0) ? (4 * 64 * 68) : ((BM + BN) * 64);
  __shared__ ushort smem[SMEM];
  ushort* As = smem;
  ushort* Bs = smem + BM * 64;

  const int tid = threadIdx.x;
  const int lane = tid & 63;
  const int w = tid >> 6;
  const int l31 = lane & 31;
  const int hi = lane >> 5;
  const int wm = w / WN, wn = w % WN;
  const int m0 = blockIdx.y * BM, n0 = blockIdx.x * BN;
  const int r8 = lane >> 3, c8 = lane & 7;
  const int csw = (c8 ^ r8) * 8;

  f32x16 acc[2][NT];
#pragma unroll
  for (int mt = 0; mt < 2; mt++)
#pragma unroll
    for (int nt = 0; nt < NT; nt++) acc[mt][nt] = zero16();

  for (int k0 = 0; k0 < Kd; k0 += 64) {
    __syncthreads();
#pragma unroll
    for (int ci = 0; ci < CPW; ci++) {
      const int chk = w * CPW + ci;
      if (chk < CH_A) {
        gload16(A + (size_t)(m0 + chk * 8 + r8) * Kd + k0 + csw, (char*)As + chk * 1024);
      } else {
        const int ch2 = chk - CH_A;
        gload16(Bt + (size_t)(n0 + ch2 * 8 + r8) * Kd + k0 + csw, (char*)Bs + ch2 * 1024);
      }
    }
    __syncthreads();
#pragma unroll
    for (int ks = 0; ks < 4; ks++) {
      bf16x8 af[2], bf[NT];
#pragma unroll
      for (int mt = 0; mt < 2; mt++) {
        const int rl = wm * 64 + mt * 32 + l31;
        af[mt] = *reinterpret_cast<const bf16x8*>(
            &As[rl * 64 + ((ks * 16 + hi * 8) ^ ((rl & 7) * 8))]);
      }
#pragma unroll
      for (int nt = 0; nt < NT; nt++) {
        const int nl = wn * WTN + nt * 32 + l31;
        bf[nt] = *reinterpret_cast<const bf16x8*>(
            &Bs[nl * 64 + ((ks * 16 + hi * 8) ^ ((nl & 7) * 8))]);
      }
#pragma unroll
      for (int mt = 0; mt < 2; mt++)
#pragma unroll
        for (int nt = 0; nt < NT; nt++)
          acc[mt][nt] = __builtin_amdgcn_mfma_f32_32x32x16_bf16(af[mt], bf[nt], acc[mt][nt], 0, 0, 0);
    }
  }

  // C layout (verified): col = l31, row = (r&3) + 8*(r>>2) + 4*hi
  if constexpr (EPI == 0) {
    if (n0 >= 1536) {
      // V tile: bias, per-wave transpose via LDS, store V^T [bh][d][t^swz]
      __syncthreads();
      ushort* Vw = smem + w * 4352;  // [64 d][68]
      const float bv0 = bias[n0 + wn * 64 + l31];
      const float bv1 = bias[n0 + wn * 64 + 32 + l31];
#pragma unroll
      for (int mt = 0; mt < 2; mt++)
#pragma unroll
        for (int nt = 0; nt < 2; nt++) {
          const float bv = nt ? bv1 : bv0;
#pragma unroll
          for (int r = 0; r < 16; r++) {
            const int trow = mt * 32 + (r & 3) + ((r >> 2) << 3) + (hi << 2);
            Vw[(nt * 32 + l31) * 68 + trow] = f2b(acc[mt][nt][r] + bv);
          }
        }
      const int hh = (n0 - 1536) / 64 + wn;
      const int bb = m0 >> 12;
      const int t0 = (m0 & (T - 1)) + wm * 64;
      const size_t vbase = (size_t)((bb * H + hh) * 64 + lane) * T + t0;
#pragma unroll
      for (int x8 = 0; x8 < 8; x8++) {
        bf16x8 vv = *reinterpret_cast<const bf16x8*>(&Vw[lane * 68 + x8 * 8]);
        *reinterpret_cast<bf16x8*>(vo + vbase + ((x8 ^ (lane & 7)) * 8)) = vv;
      }
    } else {
#pragma unroll
      for (int mt = 0; mt < 2; mt++)
#pragma unroll
        for (int nt = 0; nt < 2; nt++) {
          const int n = n0 + wn * 64 + nt * 32 + l31;
          const float bv = bias[n];
          const int part = (n >= 768) ? 1 : 0;
          const int ci = n - part * 768;
          const int hh = ci >> 6, dd = ci & 63;
#pragma unroll
          for (int r = 0; r < 16; r++) {
            const int m = m0 + wm * 64 + mt * 32 + (r & 3) + ((r >> 2) << 3) + (hi << 2);
            const int bb = m >> 12, t = m & (T - 1);
            const float val = acc[mt][nt][r] + bv;
            if (part == 0) {
              qo[((size_t)(bb * H + hh) * T + t) * HD + dd] = f2b(val * QSCALE);
            } else {
              ko[((size_t)(bb * H + hh) * T + t) * HD + (dd ^ ((t & 7) << 3))] = f2b(val);
            }
          }
        }
    }
  } else {
#pragma unroll
    for (int mt = 0; mt < 2; mt++)
#pragma unroll
      for (int nt = 0; nt < NT; nt++) {
        const int n = n0 + wn * WTN + nt * 32 + l31;
        const float bv = bias[n];
#pragma unroll
        for (int r = 0; r < 16; r++) {
          const int m = m0 + wm * 64 + mt * 32 + (r & 3) + ((r >> 2) << 3) + (hi << 2);
          fo[(size_t)m * N + n] = acc[mt][nt][r] + bv;
        }
      }
  }
}

// Flash attention v7: round-5 structure (paired q-tiles, uniform 65 kv-tiles/block,
// double-buffered LDS, counted vmcnt) + raw v_exp_f32 softmax + 4-chain reductions.
__global__ __launch_bounds__(128, 2) void attn_kernel(
    const ushort* __restrict__ Qg, const ushort* __restrict__ Kg,
    const ushort* __restrict__ Vtg, ushort* __restrict__ Yg) {
  // smem: buf0{K,V} | buf1{K,V} | per-wave Yt [32][36]
  __shared__ ushort smem[16384 + 2 * 32 * 36];

  const int tid = threadIdx.x;
  const int lane = tid & 63;
  const int w = tid >> 6;
  const int l31 = lane & 31;
  const int hi = lane >> 5;
  const int r8 = lane >> 3, c8 = lane & 7;

  // bid -> (bh, a): XCD-grouped (3 heads per XCD), uniform work (65 tiles each)
  const int bid = blockIdx.x;
  const int xcd = bid & 7, idx = bid >> 3;
  const int bh = xcd * 3 + idx % 3;
  const int a = idx / 3;  // 0..31: passes qt=a then qt=63-a

  const int bb = bh / H, h = bh % H;
  const ushort* Qp = Qg + (size_t)bh * T * HD;
  const char* Kbp = (const char*)(Kg + (size_t)bh * T * HD);
  const char* Vbp = (const char*)(Vtg + (size_t)bh * HD * T);

  // Q B-fragments for both passes
  bf16x8 qfa[4], qfb[4], qcur[4];
  const int qr0 = a * 64 + w * 32 + l31;
  const int qr1 = (63 - a) * 64 + w * 32 + l31;
#pragma unroll
  for (int ks = 0; ks < 4; ks++) {
    qfa[ks] = *reinterpret_cast<const bf16x8*>(Qp + (size_t)qr0 * HD + ks * 16 + hi * 8);
    qfb[ks] = *reinterpret_cast<const bf16x8*>(Qp + (size_t)qr1 * HD + ks * 16 + hi * 8);
    qcur[ks] = qfa[ks];
  }

  int q0 = a * 64;
  int q0w = q0 + w * 32;
  int qc = q0w + l31;

  float mrun = -1e30f, lrun = 0.f;
  f32x16 o16[2];
  o16[0] = zero16();
  o16[1] = zero16();

  const int boundary = a + 1;       // first tile index of pass1
  const int nt_tot = 65;

  auto kv0_of = [&](int tt) { return (tt < boundary ? tt : tt - boundary) * 64; };

  auto issue_tile = [&](int tt) {
    const int kv0 = kv0_of(tt);
    ushort* kb = smem + (tt & 1) * 8192;
    ushort* vb = kb + 4096;
#pragma unroll
    for (int c2 = 0; c2 < 4; c2++) {
      const int chk = w * 4 + c2;
      gload16(Kbp + ((size_t)(kv0 + chk * 8 + r8) * 64 + c8 * 8) * 2, (char*)kb + chk * 1024);
      gload16(Vbp + ((size_t)(chk * 8 + r8) * T + kv0 + c8 * 8) * 2, (char*)vb + chk * 1024);
    }
  };

  auto epilogue = [&](int q0p, float lr) {
    ushort* Yt = smem + 16384 + w * 1152;  // [32 q][36]
    const float linv = 1.0f / lr;
#pragma unroll
    for (int dt = 0; dt < 2; dt++) {
#pragma unroll
      for (int r = 0; r < 16; r++) {
        const int d32 = (r & 3) + ((r >> 2) << 3) + (hi << 2);
        Yt[l31 * 36 + d32] = f2b(o16[dt][r] * linv);
      }
#pragma unroll
      for (int seg = 0; seg < 2; seg++) {
        bf16x8 vv = *reinterpret_cast<const bf16x8*>(&Yt[l31 * 36 + hi * 16 + seg * 8]);
        *reinterpret_cast<bf16x8*>(
            Yg + ((size_t)(bb * T + q0p + w * 32 + l31)) * C + h * 64 + dt * 32 + hi * 16 + seg * 8) = vv;
      }
    }
  };

  issue_tile(0);

  for (int tt = 0; tt < nt_tot; tt++) {
    if (tt + 1 < nt_tot) {
      issue_tile(tt + 1);
      asm volatile("s_waitcnt vmcnt(8)" ::: "memory");
    } else {
      asm volatile("s_waitcnt vmcnt(0)" ::: "memory");
    }
    __builtin_amdgcn_s_barrier();
    __builtin_amdgcn_sched_barrier(0);

    if (tt == boundary) {
      // flush pass0, reset state for pass1
      epilogue(q0, lrun);
      mrun = -1e30f; lrun = 0.f;
      o16[0] = zero16(); o16[1] = zero16();
#pragma unroll
      for (int ks = 0; ks < 4; ks++) qcur[ks] = qfb[ks];
      q0 = (63 - a) * 64;
      q0w = q0 + w * 32;
      qc = q0w + l31;
    }

    const int kv0 = kv0_of(tt);
    const ushort* Ks = smem + (tt & 1) * 8192;
    const ushort* Vs = Ks + 4096;

    const bool have[2] = {kv0 <= q0w + 31, kv0 + 32 <= q0w + 31};
    const bool needm[2] = {kv0 + 31 > q0w, kv0 + 63 > q0w};

    // S^T = K x Q^T
    f32x16 s2[2];
    s2[0] = zero16();
    s2[1] = zero16();
    __builtin_amdgcn_s_setprio(1);
#pragma unroll
    for (int sub = 0; sub < 2; sub++) {
      if (!have[sub]) continue;
      const int row = sub * 32 + l31;
      const int sw = (row & 7) << 3;
#pragma unroll
      for (int ks = 0; ks < 4; ks++) {
        bf16x8 kf = *reinterpret_cast<const bf16x8*>(&Ks[row * 64 + ((ks * 16 + hi * 8) ^ sw)]);
        s2[sub] = __builtin_amdgcn_mfma_f32_32x32x16_bf16(kf, qcur[ks], s2[sub], 0, 0, 0);
      }
      if (needm[sub]) {
#pragma unroll
        for (int r2 = 0; r2 < 16; r2++) {
          const int kv = kv0 + sub * 32 + (r2 & 3) + ((r2 >> 2) << 3) + (hi << 2);
          if (kv > qc) s2[sub][r2] = -1e30f;
        }
      }
    }
    __builtin_amdgcn_s_setprio(0);

    // online softmax (per-lane q = l31), defer-max THR=8, 4 parallel chains
    float pa = -1e30f, pb = -1e30f, pc = -1e30f, pd = -1e30f;
#pragma unroll
    for (int sub = 0; sub < 2; sub++) {
      if (!have[sub]) continue;
#pragma unroll
      for (int r2 = 0; r2 < 16; r2 += 4) {
        pa = fmaxf(pa, s2[sub][r2]);
        pb = fmaxf(pb, s2[sub][r2 + 1]);
        pc = fmaxf(pc, s2[sub][r2 + 2]);
        pd = fmaxf(pd, s2[sub][r2 + 3]);
      }
    }
    float pm = fmaxf(fmaxf(pa, pb), fmaxf(pc, pd));
    pm = fmaxf(pm, __shfl_xor(pm, 32));
    if (__any(pm > mrun + 8.f)) {
      const float mnew = fmaxf(mrun, pm);
      const float corr = __builtin_amdgcn_exp2f(mrun - mnew);
      lrun *= corr;
#pragma unroll
      for (int dt = 0; dt < 2; dt++)
#pragma unroll
        for (int r2 = 0; r2 < 16; r2++) o16[dt][r2] *= corr;
      mrun = mnew;
    }
    float sa = 0.f, sb = 0.f, sc = 0.f, sd = 0.f;
#pragma unroll
    for (int sub = 0; sub < 2; sub++) {
      if (!have[sub]) continue;
#pragma unroll
      for (int r2 = 0; r2 < 16; r2 += 4) {
        s2[sub][r2]     = __builtin_amdgcn_exp2f(s2[sub][r2] - mrun);     sa += s2[sub][r2];
        s2[sub][r2 + 1] = __builtin_amdgcn_exp2f(s2[sub][r2 + 1] - mrun); sb += s2[sub][r2 + 1];
        s2[sub][r2 + 2] = __builtin_amdgcn_exp2f(s2[sub][r2 + 2] - mrun); sc += s2[sub][r2 + 2];
        s2[sub][r2 + 3] = __builtin_amdgcn_exp2f(s2[sub][r2 + 3] - mrun); sd += s2[sub][r2 + 3];
      }
    }
    float sum = (sa + sb) + (sc + sd);
    sum += __shfl_xor(sum, 32);
    lrun += sum;

    // P^T B-frag in-register, then O^T += V^T x P^T
#pragma unroll
    for (int sub = 0; sub < 2; sub++) {
      if (!have[sub]) continue;
#pragma unroll
      for (int ks2 = 0; ks2 < 2; ks2++) {
        const int r0 = ks2 * 8;
        int a0, a1, b0, b1;
        asm("v_cvt_pk_bf16_f32 %0, %1, %2" : "=v"(a0) : "v"(s2[sub][r0 + 0]), "v"(s2[sub][r0 + 1]));
        asm("v_cvt_pk_bf16_f32 %0, %1, %2" : "=v"(a1) : "v"(s2[sub][r0 + 2]), "v"(s2[sub][r0 + 3]));
        asm("v_cvt_pk_bf16_f32 %0, %1, %2" : "=v"(b0) : "v"(s2[sub][r0 + 4]), "v"(s2[sub][r0 + 5]));
        asm("v_cvt_pk_bf16_f32 %0, %1, %2" : "=v"(b1) : "v"(s2[sub][r0 + 6]), "v"(s2[sub][r0 + 7]));
        asm("v_permlane32_swap_b32 %0, %1" : "+v"(a0), "+v"(b0));
        asm("v_permlane32_swap_b32 %0, %1" : "+v"(a1), "+v"(b1));
        const i32x4 pi = {a0, a1, b0, b1};
        const bf16x8 pf = __builtin_bit_cast(bf16x8, pi);
        __builtin_amdgcn_s_setprio(1);
#pragma unroll
        for (int dt = 0; dt < 2; dt++) {
          const int drow = dt * 32 + l31;
          const int sw = (drow & 7) << 3;
          bf16x8 vf = *reinterpret_cast<const bf16x8*>(
              &Vs[drow * 64 + ((sub * 32 + ks2 * 16 + hi * 8) ^ sw)]);
          o16[dt] = __builtin_amdgcn_mfma_f32_32x32x16_bf16(vf, pf, o16[dt], 0, 0, 0);
        }
        __builtin_amdgcn_s_setprio(0);
      }
    }

    asm volatile("s_waitcnt lgkmcnt(0)" ::: "memory");
    __builtin_amdgcn_s_barrier();
  }  // tt

  epilogue(q0, lrun);
}

extern "C" void kernel_launch(void* const* d_in, const int* in_sizes, int n_in,
                              void* d_out, int out_size, void* d_ws, size_t ws_size,
                              hipStream_t stream) {
  const float* x = (const float*)d_in[0];
  const float* Wa = (const float*)d_in[1];
  const float* ba = (const float*)d_in[2];
  const float* Wp = (const float*)d_in[3];
  const float* bp = (const float*)d_in[4];
  float* out = (float*)d_out;

  char* ws = (char*)d_ws;
  size_t off = 0;
  auto carve = [&](size_t bytes) {
    void* p = ws + off;
    off += (bytes + 255) & ~(size_t)255;
    return p;
  };
  ushort* xb   = (ushort*)carve((size_t)M * C * 2);
  ushort* WaT  = (ushort*)carve((size_t)N3 * C * 2);
  ushort* WpT  = (ushort*)carve((size_t)C * C * 2);
  ushort* Qb   = (ushort*)carve((size_t)BH * T * HD * 2);
  ushort* Kb   = (ushort*)carve((size_t)BH * T * HD * 2);
  ushort* Vtb  = (ushort*)carve((size_t)BH * HD * T * 2);
  ushort* Yb   = (ushort*)carve((size_t)M * C * 2);

  cvt_kernel<<<2048, 256, 0, stream>>>(x, xb, M * C);
  cvtT_kernel<<<dim3(C / 64, N3 / 64), 256, 0, stream>>>(Wa, WaT, C, N3);
  cvtT_kernel<<<dim3(C / 64, C / 64), 256, 0, stream>>>(Wp, WpT, C, C);

  gemm_kernel<0><<<dim3(N3 / 128, M / 128), 256, 0, stream>>>(
      xb, WaT, ba, N3, C, Qb, Kb, Vtb, nullptr);

  attn_kernel<<<dim3(768), 128, 0, stream>>>(Qb, Kb, Vtb, Yb);

  gemm_kernel<1><<<dim3(C / 128, M / 64), 256, 0, stream>>>(
      Yb, WpT, bp, C, C, nullptr, nullptr, nullptr, out);
}

// Round 8
// 178.632 us; speedup vs baseline: 2.0970x; 1.1032x over previous
//
#include <hip/hip_runtime.h>
#include <hip/hip_bf16.h>

typedef __attribute__((ext_vector_type(8))) short bf16x8;
typedef __attribute__((ext_vector_type(4))) float f32x4;
typedef __attribute__((ext_vector_type(16))) float f32x16;
typedef __attribute__((ext_vector_type(4))) int i32x4;

#define DEVI __device__ __forceinline__

namespace {
constexpr int BATCH = 2;
constexpr int T = 4096;
constexpr int C = 768;
constexpr int H = 12;
constexpr int HD = 64;
constexpr int M = BATCH * T;     // 8192
constexpr int N3 = 3 * C;        // 2304
constexpr int BH = BATCH * H;    // 24
constexpr float QSCALE = 0.125f * 1.44269504088896f;  // 1/sqrt(64) * log2(e)
constexpr int PSZ = 64 * 64 + 128;  // partial: O^T f32 + l[64] + m[64]
}  // namespace

DEVI ushort f2b(float f) {
  union { float f; unsigned u; } v; v.f = f;
  unsigned r = (v.u + 0x7FFFu + ((v.u >> 16) & 1u)) >> 16;
  return (ushort)r;
}

DEVI f32x16 zero16() {
  f32x16 z;
#pragma unroll
  for (int i = 0; i < 16; i++) z[i] = 0.f;
  return z;
}

// async 16B global->LDS. LDS dest is wave-uniform base; HW adds lane*16.
DEVI void gload16(const void* g, void* l) {
  __builtin_amdgcn_global_load_lds(
      (const __attribute__((address_space(1))) unsigned int*)g,
      (__attribute__((address_space(3))) unsigned int*)l, 16, 0, 0);
}

__global__ __launch_bounds__(256) void cvt_kernel(const float* __restrict__ src,
                                                  ushort* __restrict__ dst, int n) {
  int i = (blockIdx.x * 256 + threadIdx.x) * 4;
  int stride = gridDim.x * 256 * 4;
  for (; i < n; i += stride) {
    float4 v = *reinterpret_cast<const float4*>(src + i);
    ushort4 o;
    o.x = f2b(v.x); o.y = f2b(v.y); o.z = f2b(v.z); o.w = f2b(v.w);
    *reinterpret_cast<ushort4*>(dst + i) = o;
  }
}

// Transpose-convert: f32 W [K][N] -> bf16 W^T [N][K]. 64x64 tiles.
__global__ __launch_bounds__(256) void cvtT_kernel(const float* __restrict__ src,
                                                   ushort* __restrict__ dst,
                                                   int K, int N) {
  __shared__ ushort Lt[64 * 68];
  const int k0 = blockIdx.x * 64, n0 = blockIdx.y * 64;
  const int tid = threadIdx.x;
  const int rr = tid >> 4, c4 = (tid & 15) * 4;
#pragma unroll
  for (int it = 0; it < 4; it++) {
    const int r = it * 16 + rr;
    float4 v = *reinterpret_cast<const float4*>(src + (size_t)(k0 + r) * N + n0 + c4);
    Lt[(c4 + 0) * 68 + r] = f2b(v.x);
    Lt[(c4 + 1) * 68 + r] = f2b(v.y);
    Lt[(c4 + 2) * 68 + r] = f2b(v.z);
    Lt[(c4 + 3) * 68 + r] = f2b(v.w);
  }
  __syncthreads();
#pragma unroll
  for (int it = 0; it < 4; it++) {
    const int r = it * 16 + rr;
    *reinterpret_cast<ushort4*>(dst + (size_t)(n0 + r) * K + k0 + c4) =
        *reinterpret_cast<const ushort4*>(&Lt[r * 68 + c4]);
  }
}

// m97-style GEMM: A [Mrows x Kd] bf16 row-major, Bt = B^T [N x Kd] bf16 row-major.
template <int EPI>
__global__ __launch_bounds__(256, 3) void gemm_kernel(
    const ushort* __restrict__ A, const ushort* __restrict__ Bt,
    const float* __restrict__ bias, int N, int Kd,
    ushort* __restrict__ qo, ushort* __restrict__ ko, ushort* __restrict__ vo,
    float* __restrict__ fo) {
  constexpr int BM = (EPI == 0) ? 128 : 64;
  constexpr int BN = 128;
  constexpr int WN = (EPI == 0) ? 2 : 4;   // waves along n
  constexpr int WTN = BN / WN;             // 64 or 32
  constexpr int NT = WTN / 32;             // 2 or 1
  constexpr int CH_A = BM / 8;             // 1KB chunks in A tile
  constexpr int CH_B = BN / 8;
  constexpr int CPW = (CH_A + CH_B) / 4;
  constexpr int SMEM = (EPI == 0) ? (4 * 64 * 68) : ((BM + BN) * 64);
  __shared__ ushort smem[SMEM];
  ushort* As = smem;
  ushort* Bs = smem + BM * 64;

  const int tid = threadIdx.x;
  const int lane = tid & 63;
  const int w = tid >> 6;
  const int l31 = lane & 31;
  const int hi = lane >> 5;
  const int wm = w / WN, wn = w % WN;
  const int m0 = blockIdx.y * BM, n0 = blockIdx.x * BN;
  const int r8 = lane >> 3, c8 = lane & 7;
  const int csw = (c8 ^ r8) * 8;

  f32x16 acc[2][NT];
#pragma unroll
  for (int mt = 0; mt < 2; mt++)
#pragma unroll
    for (int nt = 0; nt < NT; nt++) acc[mt][nt] = zero16();

  for (int k0 = 0; k0 < Kd; k0 += 64) {
    __syncthreads();
#pragma unroll
    for (int ci = 0; ci < CPW; ci++) {
      const int chk = w * CPW + ci;
      if (chk < CH_A) {
        gload16(A + (size_t)(m0 + chk * 8 + r8) * Kd + k0 + csw, (char*)As + chk * 1024);
      } else {
        const int ch2 = chk - CH_A;
        gload16(Bt + (size_t)(n0 + ch2 * 8 + r8) * Kd + k0 + csw, (char*)Bs + ch2 * 1024);
      }
    }
    __syncthreads();
#pragma unroll
    for (int ks = 0; ks < 4; ks++) {
      bf16x8 af[2], bf[NT];
#pragma unroll
      for (int mt = 0; mt < 2; mt++) {
        const int rl = wm * 64 + mt * 32 + l31;
        af[mt] = *reinterpret_cast<const bf16x8*>(
            &As[rl * 64 + ((ks * 16 + hi * 8) ^ ((rl & 7) * 8))]);
      }
#pragma unroll
      for (int nt = 0; nt < NT; nt++) {
        const int nl = wn * WTN + nt * 32 + l31;
        bf[nt] = *reinterpret_cast<const bf16x8*>(
            &Bs[nl * 64 + ((ks * 16 + hi * 8) ^ ((nl & 7) * 8))]);
      }
#pragma unroll
      for (int mt = 0; mt < 2; mt++)
#pragma unroll
        for (int nt = 0; nt < NT; nt++)
          acc[mt][nt] = __builtin_amdgcn_mfma_f32_32x32x16_bf16(af[mt], bf[nt], acc[mt][nt], 0, 0, 0);
    }
  }

  // C layout (verified): col = l31, row = (r&3) + 8*(r>>2) + 4*hi
  if constexpr (EPI == 0) {
    if (n0 >= 1536) {
      __syncthreads();
      ushort* Vw = smem + w * 4352;  // [64 d][68]
      const float bv0 = bias[n0 + wn * 64 + l31];
      const float bv1 = bias[n0 + wn * 64 + 32 + l31];
#pragma unroll
      for (int mt = 0; mt < 2; mt++)
#pragma unroll
        for (int nt = 0; nt < 2; nt++) {
          const float bv = nt ? bv1 : bv0;
#pragma unroll
          for (int r = 0; r < 16; r++) {
            const int trow = mt * 32 + (r & 3) + ((r >> 2) << 3) + (hi << 2);
            Vw[(nt * 32 + l31) * 68 + trow] = f2b(acc[mt][nt][r] + bv);
          }
        }
      const int hh = (n0 - 1536) / 64 + wn;
      const int bb = m0 >> 12;
      const int t0 = (m0 & (T - 1)) + wm * 64;
      const size_t vbase = (size_t)((bb * H + hh) * 64 + lane) * T + t0;
#pragma unroll
      for (int x8 = 0; x8 < 8; x8++) {
        bf16x8 vv = *reinterpret_cast<const bf16x8*>(&Vw[lane * 68 + x8 * 8]);
        *reinterpret_cast<bf16x8*>(vo + vbase + ((x8 ^ (lane & 7)) * 8)) = vv;
      }
    } else {
#pragma unroll
      for (int mt = 0; mt < 2; mt++)
#pragma unroll
        for (int nt = 0; nt < 2; nt++) {
          const int n = n0 + wn * 64 + nt * 32 + l31;
          const float bv = bias[n];
          const int part = (n >= 768) ? 1 : 0;
          const int ci = n - part * 768;
          const int hh = ci >> 6, dd = ci & 63;
#pragma unroll
          for (int r = 0; r < 16; r++) {
            const int m = m0 + wm * 64 + mt * 32 + (r & 3) + ((r >> 2) << 3) + (hi << 2);
            const int bb = m >> 12, t = m & (T - 1);
            const float val = acc[mt][nt][r] + bv;
            if (part == 0) {
              qo[((size_t)(bb * H + hh) * T + t) * HD + dd] = f2b(val * QSCALE);
            } else {
              ko[((size_t)(bb * H + hh) * T + t) * HD + (dd ^ ((t & 7) << 3))] = f2b(val);
            }
          }
        }
    }
  } else {
#pragma unroll
    for (int mt = 0; mt < 2; mt++)
#pragma unroll
      for (int nt = 0; nt < NT; nt++) {
        const int n = n0 + wn * WTN + nt * 32 + l31;
        const float bv = bias[n];
#pragma unroll
        for (int r = 0; r < 16; r++) {
          const int m = m0 + wm * 64 + mt * 32 + (r & 3) + ((r >> 2) << 3) + (hi << 2);
          fo[(size_t)m * N + n] = acc[mt][nt][r] + bv;
        }
      }
  }
}

// Flash attention v8: kv-split uniform jobs, all-resident, single-buffered K/V
// with split-issue pipeline. 1536 blocks x 128 thr (2 waves x 32 q).
// slot<16: direct pair (qt=a, 31-a). 16<=slot<48: chunk1 of qt=slot+16 (kv<2048,
// partial). slot>=48: chunk2 pair (qt=32+a, 63-a; kv>=2048, partial).
__global__ __launch_bounds__(128, 3) void attn_kernel(
    const ushort* __restrict__ Qg, const ushort* __restrict__ Kg,
    const ushort* __restrict__ Vtg, ushort* __restrict__ Yg,
    float* __restrict__ Pp) {
  __shared__ ushort kbuf[4096];       // K tile [64kv][64k^swz]
  __shared__ ushort vbuf[4096];       // V^T tile [64d][64kv^swz]
  __shared__ ushort Yt[2 * 32 * 36];  // per-wave epilogue transpose

  const int tid = threadIdx.x;
  const int lane = tid & 63;
  const int w = tid >> 6;
  const int l31 = lane & 31;
  const int hi = lane >> 5;
  const int r8 = lane >> 3, c8 = lane & 7;

  const int bid = blockIdx.x;
  const int xcd = bid & 7;
  const int bh = xcd * 3 + (bid >> 3) % 3;   // 3 heads per XCD
  const int slot = (bid >> 3) / 3;           // 0..63

  int qtA, qtB, kvbase, bnd, ntot;
  bool partial;
  if (slot < 16) {
    qtA = slot; qtB = 31 - slot; kvbase = 0; bnd = slot + 1; ntot = 33; partial = false;
  } else if (slot < 48) {
    qtA = slot + 16; qtB = -1; kvbase = 0; bnd = 32; ntot = 32; partial = true;
  } else {
    const int a = slot - 48;
    qtA = 32 + a; qtB = 63 - a; kvbase = 32; bnd = a + 1; ntot = 33; partial = true;
  }

  const int bb = bh / H, h = bh % H;
  const ushort* Qp = Qg + (size_t)bh * T * HD;
  const char* Kbp = (const char*)(Kg + (size_t)bh * T * HD);
  const char* Vbp = (const char*)(Vtg + (size_t)bh * HD * T);

  bf16x8 qfa[4], qfb[4], qcur[4];
#pragma unroll
  for (int ks = 0; ks < 4; ks++) {
    qfa[ks] = *reinterpret_cast<const bf16x8*>(
        Qp + (size_t)(qtA * 64 + w * 32 + l31) * HD + ks * 16 + hi * 8);
    qcur[ks] = qfa[ks];
  }
  if (qtB >= 0) {
#pragma unroll
    for (int ks = 0; ks < 4; ks++)
      qfb[ks] = *reinterpret_cast<const bf16x8*>(
          Qp + (size_t)(qtB * 64 + w * 32 + l31) * HD + ks * 16 + hi * 8);
  }

  int q0 = qtA * 64;
  int q0w = q0 + w * 32;
  int qc = q0w + l31;
  float* Pcur = partial ? (Pp + (size_t)((bh * 32 + (qtA - 32)) * 2 + (slot >= 48 ? 1 : 0)) * PSZ)
                        : nullptr;

  float mrun = -1e30f, lrun = 0.f;
  f32x16 o16[2];
  o16[0] = zero16();
  o16[1] = zero16();

  auto kvt_of = [&](int tt) { return kvbase + (tt < bnd ? tt : tt - bnd); };

  auto issue_K = [&](int tt) {
    const int kv0 = kvt_of(tt) * 64;
#pragma unroll
    for (int c2 = 0; c2 < 4; c2++) {
      const int chk = w * 4 + c2;
      gload16(Kbp + ((size_t)(kv0 + chk * 8 + r8) * 64 + c8 * 8) * 2, (char*)kbuf + chk * 1024);
    }
  };
  auto issue_V = [&](int tt) {
    const int kv0 = kvt_of(tt) * 64;
#pragma unroll
    for (int c2 = 0; c2 < 4; c2++) {
      const int chk = w * 4 + c2;
      gload16(Vbp + ((size_t)(chk * 8 + r8) * T + kv0 + c8 * 8) * 2, (char*)vbuf + chk * 1024);
    }
  };

  auto epilogue = [&](int q0p, float lr) {
    ushort* Yw = Yt + w * 1152;  // [32 q][36]
    const float linv = 1.0f / lr;
#pragma unroll
    for (int dt = 0; dt < 2; dt++) {
#pragma unroll
      for (int r = 0; r < 16; r++) {
        const int d32 = (r & 3) + ((r >> 2) << 3) + (hi << 2);
        Yw[l31 * 36 + d32] = f2b(o16[dt][r] * linv);
      }
#pragma unroll
      for (int seg = 0; seg < 2; seg++) {
        bf16x8 vv = *reinterpret_cast<const bf16x8*>(&Yw[l31 * 36 + hi * 16 + seg * 8]);
        *reinterpret_cast<bf16x8*>(
            Yg + ((size_t)(bb * T + q0p + w * 32 + l31)) * C + h * 64 + dt * 32 + hi * 16 + seg * 8) = vv;
      }
    }
  };

  auto pwrite = [&](float* P, float lr, float mr) {
#pragma unroll
    for (int dt = 0; dt < 2; dt++)
#pragma unroll
      for (int r = 0; r < 16; r++) {
        const int d = dt * 32 + (r & 3) + ((r >> 2) << 3) + (hi << 2);
        P[d * 64 + w * 32 + l31] = o16[dt][r];
      }
    P[4096 + w * 32 + l31] = lr;
    P[4160 + w * 32 + l31] = mr;
  };

  issue_K(0);

  for (int tt = 0; tt < ntot; tt++) {
    asm volatile("s_waitcnt vmcnt(0)" ::: "memory");
    __builtin_amdgcn_s_barrier();
    __builtin_amdgcn_sched_barrier(0);

    if (tt == bnd) {  // flush pass A (pairs only), switch state to pass B
      if (partial) pwrite(Pcur, lrun, mrun);
      else epilogue(q0, lrun);
      mrun = -1e30f; lrun = 0.f;
      o16[0] = zero16(); o16[1] = zero16();
#pragma unroll
      for (int ks = 0; ks < 4; ks++) qcur[ks] = qfb[ks];
      q0 = qtB * 64;
      q0w = q0 + w * 32;
      qc = q0w + l31;
      if (partial) Pcur = Pp + (size_t)((bh * 32 + (qtB - 32)) * 2 + 1) * PSZ;
    }

    issue_V(tt);

    const int kv0 = kvt_of(tt) * 64;
    const bool have[2] = {kv0 <= q0w + 31, kv0 + 32 <= q0w + 31};
    const bool needm[2] = {kv0 + 31 > q0w, kv0 + 63 > q0w};

    // S^T = K x Q^T (kbuf resident)
    f32x16 s2[2];
    s2[0] = zero16();
    s2[1] = zero16();
    __builtin_amdgcn_s_setprio(1);
#pragma unroll
    for (int sub = 0; sub < 2; sub++) {
      if (!have[sub]) continue;
      const int row = sub * 32 + l31;
      const int sw = (row & 7) << 3;
#pragma unroll
      for (int ks = 0; ks < 4; ks++) {
        bf16x8 kf = *reinterpret_cast<const bf16x8*>(
            &kbuf[row * 64 + ((ks * 16 + hi * 8) ^ sw)]);
        s2[sub] = __builtin_amdgcn_mfma_f32_32x32x16_bf16(kf, qcur[ks], s2[sub], 0, 0, 0);
      }
      if (needm[sub]) {
#pragma unroll
        for (int r2 = 0; r2 < 16; r2++) {
          const int kv = kv0 + sub * 32 + (r2 & 3) + ((r2 >> 2) << 3) + (hi << 2);
          if (kv > qc) s2[sub][r2] = -1e30f;
        }
      }
    }
    __builtin_amdgcn_s_setprio(0);

    asm volatile("s_waitcnt lgkmcnt(0)" ::: "memory");
    __builtin_amdgcn_s_barrier();           // kbuf fully consumed by all waves
    __builtin_amdgcn_sched_barrier(0);
    if (tt + 1 < ntot) issue_K(tt + 1);     // K prefetch flies under softmax+PV

    // online softmax (per-lane q = l31), defer-max THR=8
    float pa = -1e30f, pb = -1e30f, pc = -1e30f, pd = -1e30f;
#pragma unroll
    for (int sub = 0; sub < 2; sub++) {
      if (!have[sub]) continue;
#pragma unroll
      for (int r2 = 0; r2 < 16; r2 += 4) {
        pa = fmaxf(pa, s2[sub][r2]);
        pb = fmaxf(pb, s2[sub][r2 + 1]);
        pc = fmaxf(pc, s2[sub][r2 + 2]);
        pd = fmaxf(pd, s2[sub][r2 + 3]);
      }
    }
    float pm = fmaxf(fmaxf(pa, pb), fmaxf(pc, pd));
    pm = fmaxf(pm, __shfl_xor(pm, 32));
    if (__any(pm > mrun + 8.f)) {
      const float mnew = fmaxf(mrun, pm);
      const float corr = __builtin_amdgcn_exp2f(mrun - mnew);
      lrun *= corr;
#pragma unroll
      for (int dt = 0; dt < 2; dt++)
#pragma unroll
        for (int r2 = 0; r2 < 16; r2++) o16[dt][r2] *= corr;
      mrun = mnew;
    }
    float sa = 0.f, sb = 0.f, sc = 0.f, sd = 0.f;
#pragma unroll
    for (int sub = 0; sub < 2; sub++) {
      if (!have[sub]) continue;
#pragma unroll
      for (int r2 = 0; r2 < 16; r2 += 4) {
        s2[sub][r2]     = __builtin_amdgcn_exp2f(s2[sub][r2] - mrun);     sa += s2[sub][r2];
        s2[sub][r2 + 1] = __builtin_amdgcn_exp2f(s2[sub][r2 + 1] - mrun); sb += s2[sub][r2 + 1];
        s2[sub][r2 + 2] = __builtin_amdgcn_exp2f(s2[sub][r2 + 2] - mrun); sc += s2[sub][r2 + 2];
        s2[sub][r2 + 3] = __builtin_amdgcn_exp2f(s2[sub][r2 + 3] - mrun); sd += s2[sub][r2 + 3];
      }
    }
    float sum = (sa + sb) + (sc + sd);
    sum += __shfl_xor(sum, 32);
    lrun += sum;

    // wait for V (counted: only K(tt+1) may remain in flight), then PV
    if (tt + 1 < ntot) {
      asm volatile("s_waitcnt vmcnt(4)" ::: "memory");
    } else {
      asm volatile("s_waitcnt vmcnt(0)" ::: "memory");
    }
    __builtin_amdgcn_s_barrier();           // all waves' V chunks arrived
    __builtin_amdgcn_sched_barrier(0);

#pragma unroll
    for (int sub = 0; sub < 2; sub++) {
      if (!have[sub]) continue;
#pragma unroll
      for (int ks2 = 0; ks2 < 2; ks2++) {
        const int r0 = ks2 * 8;
        int a0, a1, b0, b1;
        asm("v_cvt_pk_bf16_f32 %0, %1, %2" : "=v"(a0) : "v"(s2[sub][r0 + 0]), "v"(s2[sub][r0 + 1]));
        asm("v_cvt_pk_bf16_f32 %0, %1, %2" : "=v"(a1) : "v"(s2[sub][r0 + 2]), "v"(s2[sub][r0 + 3]));
        asm("v_cvt_pk_bf16_f32 %0, %1, %2" : "=v"(b0) : "v"(s2[sub][r0 + 4]), "v"(s2[sub][r0 + 5]));
        asm("v_cvt_pk_bf16_f32 %0, %1, %2" : "=v"(b1) : "v"(s2[sub][r0 + 6]), "v"(s2[sub][r0 + 7]));
        asm("v_permlane32_swap_b32 %0, %1" : "+v"(a0), "+v"(b0));
        asm("v_permlane32_swap_b32 %0, %1" : "+v"(a1), "+v"(b1));
        const i32x4 pi = {a0, a1, b0, b1};
        const bf16x8 pf = __builtin_bit_cast(bf16x8, pi);
        __builtin_amdgcn_s_setprio(1);
#pragma unroll
        for (int dt = 0; dt < 2; dt++) {
          const int drow = dt * 32 + l31;
          const int sw = (drow & 7) << 3;
          bf16x8 vf = *reinterpret_cast<const bf16x8*>(
              &vbuf[drow * 64 + ((sub * 32 + ks2 * 16 + hi * 8) ^ sw)]);
          o16[dt] = __builtin_amdgcn_mfma_f32_32x32x16_bf16(vf, pf, o16[dt], 0, 0, 0);
        }
        __builtin_amdgcn_s_setprio(0);
      }
    }
  }  // tt

  if (partial) pwrite(Pcur, lrun, mrun);
  else epilogue(q0, lrun);
}

// Combine two kv-chunk partials per (bh, qt>=32) into Y.
__global__ __launch_bounds__(64) void combine_kernel(const float* __restrict__ Pp,
                                                     ushort* __restrict__ Yg) {
  __shared__ ushort Yt[64 * 68];
  const int bid = blockIdx.x;
  const int bh = bid >> 5, qq = bid & 31;
  const int bb = bh / H, h = bh % H;
  const int q0 = (32 + qq) * 64;
  const int q = threadIdx.x;
  const float* P1 = Pp + (size_t)((bh * 32 + qq) * 2 + 0) * PSZ;
  const float* P2 = Pp + (size_t)((bh * 32 + qq) * 2 + 1) * PSZ;
  const float l1 = P1[4096 + q], m1 = P1[4160 + q];
  const float l2 = P2[4096 + q], m2 = P2[4160 + q];
  const float Mx = fmaxf(m1, m2);
  const float w1 = __builtin_amdgcn_exp2f(m1 - Mx);
  const float w2 = __builtin_amdgcn_exp2f(m2 - Mx);
  const float inv = 1.0f / (l1 * w1 + l2 * w2);
#pragma unroll 8
  for (int d = 0; d < 64; d++) {
    const float o = P1[d * 64 + q] * w1 + P2[d * 64 + q] * w2;
    Yt[q * 68 + d] = f2b(o * inv);
  }
  __syncthreads();
#pragma unroll
  for (int seg = 0; seg < 8; seg++) {
    bf16x8 vv = *reinterpret_cast<const bf16x8*>(&Yt[q * 68 + seg * 8]);
    *reinterpret_cast<bf16x8*>(
        Yg + ((size_t)(bb * T + q0 + q)) * C + h * 64 + seg * 8) = vv;
  }
}

extern "C" void kernel_launch(void* const* d_in, const int* in_sizes, int n_in,
                              void* d_out, int out_size, void* d_ws, size_t ws_size,
                              hipStream_t stream) {
  const float* x = (const float*)d_in[0];
  const float* Wa = (const float*)d_in[1];
  const float* ba = (const float*)d_in[2];
  const float* Wp = (const float*)d_in[3];
  const float* bp = (const float*)d_in[4];
  float* out = (float*)d_out;

  char* ws = (char*)d_ws;
  size_t off = 0;
  auto carve = [&](size_t bytes) {
    void* p = ws + off;
    off += (bytes + 255) & ~(size_t)255;
    return p;
  };
  ushort* xb   = (ushort*)carve((size_t)M * C * 2);
  ushort* WaT  = (ushort*)carve((size_t)N3 * C * 2);
  ushort* WpT  = (ushort*)carve((size_t)C * C * 2);
  ushort* Qb   = (ushort*)carve((size_t)BH * T * HD * 2);
  ushort* Kb   = (ushort*)carve((size_t)BH * T * HD * 2);
  ushort* Vtb  = (ushort*)carve((size_t)BH * HD * T * 2);
  ushort* Yb   = (ushort*)carve((size_t)M * C * 2);
  float*  Pp   = (float*)carve((size_t)BH * 32 * 2 * PSZ * 4);

  cvt_kernel<<<2048, 256, 0, stream>>>(x, xb, M * C);
  cvtT_kernel<<<dim3(C / 64, N3 / 64), 256, 0, stream>>>(Wa, WaT, C, N3);
  cvtT_kernel<<<dim3(C / 64, C / 64), 256, 0, stream>>>(Wp, WpT, C, C);

  gemm_kernel<0><<<dim3(N3 / 128, M / 128), 256, 0, stream>>>(
      xb, WaT, ba, N3, C, Qb, Kb, Vtb, nullptr);

  attn_kernel<<<dim3(1536), 128, 0, stream>>>(Qb, Kb, Vtb, Yb, Pp);
  combine_kernel<<<dim3(BH * 32), 64, 0, stream>>>(Pp, Yb);

  gemm_kernel<1><<<dim3(C / 128, M / 64), 256, 0, stream>>>(
      Yb, WpT, bp, C, C, nullptr, nullptr, nullptr, out);
}